// Round 2
// baseline (1348.380 us; speedup 1.0000x reference)
//
#include <hip/hip_runtime.h>

#define DDIM 256
#define KCB  1024
#define TLEN 4096
#define BATCH 16
#define NQ (BATCH * TLEN)   // 65536

static constexpr float TAU = 0.01f;   // top-2 gap below this -> fp64 re-rank

// ---------------- kernel 1: codebook squared norms ----------------
__global__ void csq_kernel(const float* __restrict__ cb, float* __restrict__ csq) {
    const int k = blockIdx.x;          // 1024 blocks
    const int l = threadIdx.x;         // 64 threads
    const float4* row = reinterpret_cast<const float4*>(cb + (size_t)k * DDIM);
    float4 v = row[l];                 // 64 lanes x float4 = 256 floats
    float s = v.x * v.x + v.y * v.y + v.z * v.z + v.w * v.w;
#pragma unroll
    for (int off = 32; off > 0; off >>= 1) s += __shfl_down(s, off, 64);
    if (l == 0) csq[k] = s;
}

// ---------------- kernel 2: fp32 argmin with top-2 gap flagging ----------------
__launch_bounds__(256)
__global__ void argmin_kernel(const float* __restrict__ z, const float* __restrict__ cb,
                              const float* __restrict__ csq, int* __restrict__ idx,
                              int* __restrict__ count, int* __restrict__ flags) {
    __shared__ float zt[DDIM * 64];            // [d][lane] : 64 KB, bank-conflict-free
    const int tid = threadIdx.x;
    const int l = tid & 63;
    const int w = tid >> 6;
    const int n0 = blockIdx.x * 64;            // 64 consecutive queries (same b)
    const int b  = n0 >> 12;                   // n0 / TLEN
    const int t0 = n0 & (TLEN - 1);

    // stage z tile: zt[d][l] = z[b][d][t0+l], float4 global loads
    {
        const float4* z4 = reinterpret_cast<const float4*>(z + (size_t)b * DDIM * TLEN + t0);
        float4* zt4 = reinterpret_cast<float4*>(zt);
        for (int i = tid; i < DDIM * 16; i += 256) {
            const int d = i >> 4, j = i & 15;
            zt4[d * 16 + j] = z4[(size_t)d * (TLEN / 4) + j];
        }
    }
    __syncthreads();

    const int kbase = __builtin_amdgcn_readfirstlane(w) * 256;  // wave-uniform
    float best = 1e30f, second = 1e30f;
    int bi = 0;

    for (int c = 0; c < 32; ++c) {             // 32 chunks x 8 k per wave
        const int k0 = kbase + c * 8;
        const float* __restrict__ crow = cb + (size_t)k0 * DDIM;
        float acc[8] = {0.f, 0.f, 0.f, 0.f, 0.f, 0.f, 0.f, 0.f};
#pragma unroll 1
        for (int d0 = 0; d0 < DDIM; d0 += 4) {
            const float zv0 = zt[(d0 + 0) * 64 + l];
            const float zv1 = zt[(d0 + 1) * 64 + l];
            const float zv2 = zt[(d0 + 2) * 64 + l];
            const float zv3 = zt[(d0 + 3) * 64 + l];
#pragma unroll
            for (int j = 0; j < 8; ++j) {
                const float* cj = crow + j * DDIM + d0;   // uniform -> s_load
                acc[j] = fmaf(zv0, cj[0], acc[j]);
                acc[j] = fmaf(zv1, cj[1], acc[j]);
                acc[j] = fmaf(zv2, cj[2], acc[j]);
                acc[j] = fmaf(zv3, cj[3], acc[j]);
            }
        }
#pragma unroll
        for (int j = 0; j < 8; ++j) {
            // z^2 term is k-independent: dist = csq[k] - 2*dot
            const float dist = fmaf(-2.0f, acc[j], csq[k0 + j]);
            if (dist < best) { second = best; best = dist; bi = k0 + j; }
            else if (dist < second) { second = dist; }
        }
    }

    // cross-wave merge (reuse zt as scratch after barrier)
    __syncthreads();
    float* m1s = zt;                 // [4][64]
    float* m2s = zt + 256;           // [4][64]
    int*   i1s = reinterpret_cast<int*>(zt + 512);  // [4][64]
    m1s[w * 64 + l] = best;
    m2s[w * 64 + l] = second;
    i1s[w * 64 + l] = bi;
    __syncthreads();

    if (tid < 64) {
        float gb = m1s[l];
        float gs = m2s[l];
        int gi = i1s[l];
        for (int ww = 1; ww < 4; ++ww) {
            const float v1 = m1s[ww * 64 + l];
            const float v2 = m2s[ww * 64 + l];
            const int   ii = i1s[ww * 64 + l];
            if (v1 < gb) { gs = fminf(gb, v2); gb = v1; gi = ii; }
            else         { gs = fminf(gs, v1); }      // ties keep earlier (lower k)
        }
        idx[n0 + l] = gi;
        if (gs - gb < TAU) {
            const int p = atomicAdd(count, 1);
            if (p < NQ) flags[p] = n0 + l;       // capacity-bounded (defensive)
        }
    }
}

// ---------------- kernel 3: fp64 exact re-rank of flagged queries ----------------
__launch_bounds__(256)
__global__ void refine_kernel(const float* __restrict__ z, const float* __restrict__ cb,
                              int* __restrict__ idx, const int* __restrict__ count,
                              const int* __restrict__ flags) {
    __shared__ double zd[DDIM];
    __shared__ double rv[256];
    __shared__ int    ri[256];
    int cnt = count[0];
    if (cnt > NQ) cnt = NQ;                     // capacity-bounded (defensive)
    for (int i = blockIdx.x; i < cnt; i += gridDim.x) {
        const int n = flags[i];
        const int b = n >> 12, t = n & (TLEN - 1);
        __syncthreads();
        zd[threadIdx.x] = (double)z[(size_t)b * DDIM * TLEN + (size_t)threadIdx.x * TLEN + t];
        __syncthreads();
        double bestv = 1e300;
        int besti = 0;
        for (int j = 0; j < 4; ++j) {
            const int k = threadIdx.x * 4 + j;
            const float* crow = cb + (size_t)k * DDIM;
            double s = 0.0;
            for (int d = 0; d < DDIM; ++d) {
                const double diff = zd[d] - (double)crow[d];
                s = fma(diff, diff, s);
            }
            if (s < bestv) { bestv = s; besti = k; }   // k ascending -> first-min
        }
        rv[threadIdx.x] = bestv;
        ri[threadIdx.x] = besti;
        __syncthreads();
        for (int off = 128; off > 0; off >>= 1) {
            if (threadIdx.x < off) {
                const double ov = rv[threadIdx.x + off];
                const int    oi = ri[threadIdx.x + off];
                if (ov < rv[threadIdx.x] ||
                    (ov == rv[threadIdx.x] && oi < ri[threadIdx.x])) {
                    rv[threadIdx.x] = ov;
                    ri[threadIdx.x] = oi;
                }
            }
            __syncthreads();
        }
        if (threadIdx.x == 0) idx[n] = ri[0];
        __syncthreads();
    }
}

// ---------------- kernel 4: gather + transpose write ----------------
__launch_bounds__(256)
__global__ void gather_kernel(const float* __restrict__ cb, const int* __restrict__ idx,
                              float* __restrict__ out) {
    // grid 256: low 6 bits = t-chunk (1024 t's), high 2 bits = d-quarter
    const int c  = blockIdx.x & 63;
    const int dq = blockIdx.x >> 6;
    const int b  = c >> 2;
    const int t0 = (c & 3) * 1024;
    const int t  = t0 + threadIdx.x * 4;       // 4 consecutive t per thread
    const int4 iv = *reinterpret_cast<const int4*>(idx + (size_t)b * TLEN + t);
    const float* r0 = cb + (size_t)iv.x * DDIM;
    const float* r1 = cb + (size_t)iv.y * DDIM;
    const float* r2 = cb + (size_t)iv.z * DDIM;
    const float* r3 = cb + (size_t)iv.w * DDIM;
    float4* out4 = reinterpret_cast<float4*>(out + (size_t)b * DDIM * TLEN);
#pragma unroll 4
    for (int dd = 0; dd < 64; ++dd) {
        const int d = dq * 64 + dd;
        const float4 v = make_float4(r0[d], r1[d], r2[d], r3[d]);
        out4[((size_t)d * TLEN + t) >> 2] = v;
    }
}

extern "C" void kernel_launch(void* const* d_in, const int* in_sizes, int n_in,
                              void* d_out, int out_size, void* d_ws, size_t ws_size,
                              hipStream_t stream) {
    (void)in_sizes; (void)n_in; (void)out_size; (void)ws_size;
    const float* z  = (const float*)d_in[0];
    const float* cb = (const float*)d_in[1];
    float* out = (float*)d_out;

    char* ws = (char*)d_ws;
    float* csq  = (float*)ws;                                  // 4 KB
    int* idx    = (int*)(ws + 4096);                           // 256 KB
    int* count  = (int*)(ws + 4096 + NQ * 4);                  // 256 B slot
    int* flags  = (int*)(ws + 4096 + NQ * 4 + 256);            // 256 KB

    hipMemsetAsync(count, 0, 16, stream);
    csq_kernel<<<KCB, 64, 0, stream>>>(cb, csq);
    argmin_kernel<<<NQ / 64, 256, 0, stream>>>(z, cb, csq, idx, count, flags);
    refine_kernel<<<128, 256, 0, stream>>>(z, cb, idx, count, flags);
    gather_kernel<<<256, 256, 0, stream>>>(cb, idx, out);
}

// Round 3
// 267.013 us; speedup vs baseline: 5.0499x; 5.0499x over previous
//
#include <hip/hip_runtime.h>
#include <stdint.h>

#define DDIM 256
#define KCB  1024
#define TLEN 4096
#define BATCH 16
#define NQ (BATCH * TLEN)          // 65536
#define TAU_I 410                  // 0.025 * 16384 in scaled-int dist units

typedef __attribute__((ext_vector_type(8))) short s16x8;
typedef __attribute__((ext_vector_type(4))) float f32x4;

__device__ __forceinline__ unsigned short f2bf(float f) {
    uint32_t u = __float_as_uint(f);
    u += 0x7FFFu + ((u >> 16) & 1u);     // round-to-nearest-even
    return (unsigned short)(u >> 16);
}
__device__ __forceinline__ float bf2f(unsigned short h) {
    return __uint_as_float(((uint32_t)h) << 16);
}
__device__ __forceinline__ void gl_lds16(const void* g, void* l) {
    __builtin_amdgcn_global_load_lds(
        (const __attribute__((address_space(1))) void*)g,
        (__attribute__((address_space(3))) void*)l, 16, 0, 0);
}

// ---------- prep_cb: ch=bf16(c), cl=bf16(c-ch), csq_s = 16384*||c||^2 ----------
__global__ void prep_cb(const float* __restrict__ cb, unsigned short* __restrict__ ch,
                        unsigned short* __restrict__ cl, float* __restrict__ csq_s) {
    const int k = blockIdx.x, l = threadIdx.x;
    const float4 v = ((const float4*)cb)[k * 64 + l];
    float fv[4] = {v.x, v.y, v.z, v.w};
    unsigned short h[4], lo[4];
    double s = 0.0;
#pragma unroll
    for (int i = 0; i < 4; ++i) {
        h[i] = f2bf(fv[i]);
        lo[i] = f2bf(fv[i] - bf2f(h[i]));
        s += (double)fv[i] * (double)fv[i];
    }
#pragma unroll
    for (int off = 32; off; off >>= 1) s += __shfl_down(s, off, 64);
    if (l == 0) csq_s[k] = (float)(16384.0 * s);
    ((ushort4*)ch)[k * 64 + l] = make_ushort4(h[0], h[1], h[2], h[3]);
    ((ushort4*)cl)[k * 64 + l] = make_ushort4(lo[0], lo[1], lo[2], lo[3]);
}

// ---------- prep_z: transpose z[b][d][t] -> zh[n][d] bf16 (n = b*4096+t) ----------
__launch_bounds__(256)
__global__ void prep_z(const float* __restrict__ z, unsigned short* __restrict__ zh) {
    __shared__ unsigned short lds[64 * 280];
    const int tid = threadIdx.x;
    const int b = blockIdx.x >> 6, t0 = (blockIdx.x & 63) * 64;
    const int tq = tid & 15, rr = tid >> 4;    // tq: t-quad, rr: d-quad group 0..15
    const float* zb = z + (size_t)b * 1048576 + t0 + tq * 4;
    for (int it = 0; it < 4; ++it) {
        const int d0 = it * 64 + rr * 4;
        float4 v0 = *(const float4*)(zb + (size_t)(d0 + 0) * 4096);
        float4 v1 = *(const float4*)(zb + (size_t)(d0 + 1) * 4096);
        float4 v2 = *(const float4*)(zb + (size_t)(d0 + 2) * 4096);
        float4 v3 = *(const float4*)(zb + (size_t)(d0 + 3) * 4096);
        *(ushort4*)&lds[(tq * 4 + 0) * 280 + d0] = make_ushort4(f2bf(v0.x), f2bf(v1.x), f2bf(v2.x), f2bf(v3.x));
        *(ushort4*)&lds[(tq * 4 + 1) * 280 + d0] = make_ushort4(f2bf(v0.y), f2bf(v1.y), f2bf(v2.y), f2bf(v3.y));
        *(ushort4*)&lds[(tq * 4 + 2) * 280 + d0] = make_ushort4(f2bf(v0.z), f2bf(v1.z), f2bf(v2.z), f2bf(v3.z));
        *(ushort4*)&lds[(tq * 4 + 3) * 280 + d0] = make_ushort4(f2bf(v0.w), f2bf(v1.w), f2bf(v2.w), f2bf(v3.w));
    }
    __syncthreads();
    const int r0 = tid >> 5, c = tid & 31;
    for (int o = 0; o < 8; ++o) {
        const int t = o * 8 + r0;
        s16x8 v = *(const s16x8*)&lds[t * 280 + c * 8];
        *(s16x8*)(zh + (size_t)(b * 4096 + t0 + t) * 256 + c * 8) = v;
    }
}

// ---------- fused GEMM + argmin ----------
// block: 64 queries x all 1024 k. 4 waves, wave w owns k-quarter w*256? No:
// kc loop (4 chunks of 256 kcb), wave owns 64-kcb quarter within chunk.
__launch_bounds__(256, 2)
__global__ void gemm_argmin(const unsigned short* __restrict__ zh,
                            const unsigned short* __restrict__ ch,
                            const unsigned short* __restrict__ cl,
                            const float* __restrict__ csq_s,
                            int* __restrict__ idx,
                            int* __restrict__ cnt3, int* __restrict__ list3,
                            int* __restrict__ cntF, int* __restrict__ listF) {
    __shared__ unsigned short Alds[8 * 64 * 32];    // 32KB: [dc][n 64][d 32]
    __shared__ unsigned short Blds[2 * 256 * 32];   // 32KB: [mat][kcb 256][d 32]
    const int tid = threadIdx.x;
    const int l = tid & 63, w = tid >> 6;
    const int n0 = blockIdx.x * 64;
    const int lr = l >> 2, ld8 = (l & 3) * 8;
    const int fr = l & 15, fg = l >> 4;

    // stage A once: [dc][64][32], 32 segs of 1KB, 8 per wave
    for (int i = 0; i < 8; ++i) {
        const int s = w * 8 + i;
        const int dc = s >> 2, r = s & 3;
        const int nl = r * 16 + lr;
        gl_lds16(zh + (size_t)(n0 + nl) * 256 + dc * 32 + ld8,
                 &Alds[dc * 2048 + r * 512]);
    }

    f32x4 acc[4][4];
    int kb[16], ks2[16];
#pragma unroll
    for (int s = 0; s < 16; ++s) { kb[s] = 0x7FFFFFFF; ks2[s] = 0x7FFFFFFF; }
    const f32x4 vzero = {0.f, 0.f, 0.f, 0.f};

    for (int kc = 0; kc < 4; ++kc) {
#pragma unroll
        for (int mf = 0; mf < 4; ++mf)
#pragma unroll
            for (int kf = 0; kf < 4; ++kf) acc[mf][kf] = vzero;

        for (int dc = 0; dc < 8; ++dc) {
            // stage B chunk: ch/cl [256][32] each, 32 segs, 8 per wave
            for (int i = 0; i < 8; ++i) {
                const int s = w * 8 + i;
                const int mat = s >> 4, r2 = s & 15;
                const int kl = r2 * 16 + lr;
                const unsigned short* src = (mat ? cl : ch) +
                    (size_t)(kc * 256 + kl) * 256 + dc * 32 + ld8;
                gl_lds16(src, &Blds[mat * 8192 + r2 * 512]);
            }
            __syncthreads();
            s16x8 af[4], bh[4], bl2[4];
#pragma unroll
            for (int mf = 0; mf < 4; ++mf)
                af[mf] = *(const s16x8*)&Alds[dc * 2048 + (mf * 16 + fr) * 32 + fg * 8];
#pragma unroll
            for (int kf = 0; kf < 4; ++kf) {
                const int row = w * 64 + kf * 16 + fr;
                bh[kf]  = *(const s16x8*)&Blds[row * 32 + fg * 8];
                bl2[kf] = *(const s16x8*)&Blds[8192 + row * 32 + fg * 8];
            }
#pragma unroll
            for (int mf = 0; mf < 4; ++mf)
#pragma unroll
                for (int kf = 0; kf < 4; ++kf) {
                    acc[mf][kf] = __builtin_amdgcn_mfma_f32_16x16x32_bf16(af[mf], bh[kf],  acc[mf][kf], 0, 0, 0);
                    acc[mf][kf] = __builtin_amdgcn_mfma_f32_16x16x32_bf16(af[mf], bl2[kf], acc[mf][kf], 0, 0, 0);
                }
            __syncthreads();
        }
        // epilogue for this kc: dist_scaled = csq_s - 32768*dot; packed key = ikey*1024 + k
#pragma unroll
        for (int kf = 0; kf < 4; ++kf) {
            const int kg = kc * 256 + w * 64 + kf * 16 + fr;
            const float cs = csq_s[kg];
#pragma unroll
            for (int mf = 0; mf < 4; ++mf)
#pragma unroll
                for (int r = 0; r < 4; ++r) {
                    const int ikey = (int)floorf(fmaf(-32768.0f, acc[mf][kf][r], cs));
                    const int key = ikey * 1024 + kg;
                    const int s = mf * 4 + r;
                    const int nb = min(kb[s], key);
                    ks2[s] = min(ks2[s], max(kb[s], key));
                    kb[s] = nb;
                }
        }
    }

    // merge: pool of 64 (best,second) per query row
    __syncthreads();
    int2* scr = (int2*)Alds;                        // [64 n][64 slots]
#pragma unroll
    for (int s = 0; s < 16; ++s) {
        const int mf = s >> 2, r = s & 3;
        const int nl = mf * 16 + fg * 4 + r;
        scr[nl * 64 + w * 16 + fr] = make_int2(kb[s], ks2[s]);
    }
    __syncthreads();
    if (tid < 64) {
        int t1 = 0x7FFFFFFF, t2 = 0x7FFFFFFF, t3 = 0x7FFFFFFF;
        for (int j = 0; j < 64; ++j) {
            const int2 v = scr[tid * 64 + j];
            if (v.x < t1)      { t3 = t2; t2 = t1; t1 = v.x; }
            else if (v.x < t2) { t3 = t2; t2 = v.x; }
            else if (v.x < t3) { t3 = v.x; }
            if (v.y < t2)      { t3 = t2; t2 = v.y; }   // v.y >= v.x >= ... so never beats t1
            else if (v.y < t3) { t3 = v.y; }
        }
        const int n = n0 + tid;
        idx[n] = t1 & 1023;
        const int g2 = (t2 >> 10) - (t1 >> 10);
        const int g3 = (t3 >> 10) - (t1 >> 10);
        if (g3 < TAU_I) {
            const int p = atomicAdd(cntF, 1);
            if (p < NQ) listF[p] = n;
        } else if (g2 < TAU_I) {
            const int p = atomicAdd(cnt3, 1);
            if (p < NQ) {
                list3[2 * p] = n;
                list3[2 * p + 1] = (t1 & 1023) | ((t2 & 1023) << 10) | ((t3 & 1023) << 20);
            }
        }
    }
}

// ---------- refine3: exact fp64 re-rank of top-3 candidates ----------
__launch_bounds__(256)
__global__ void refine3_kernel(const float* __restrict__ z, const float* __restrict__ cb,
                               int* __restrict__ idx, const int* __restrict__ cnt3,
                               const int* __restrict__ list3) {
    __shared__ double part[3][4];
    int cnt = *cnt3; if (cnt > NQ) cnt = NQ;
    for (int i = blockIdx.x; i < cnt; i += gridDim.x) {
        const int n = list3[2 * i], packed = list3[2 * i + 1];
        const int b = n >> 12, t = n & 4095;
        const double zv = (double)z[(size_t)b * 1048576 + (size_t)threadIdx.x * 4096 + t];
#pragma unroll
        for (int j = 0; j < 3; ++j) {
            const int k = (packed >> (10 * j)) & 1023;
            const double diff = zv - (double)cb[(size_t)k * 256 + threadIdx.x];
            double s = diff * diff;
#pragma unroll
            for (int off = 32; off; off >>= 1) s += __shfl_down(s, off, 64);
            if ((threadIdx.x & 63) == 0) part[j][threadIdx.x >> 6] = s;
        }
        __syncthreads();
        if (threadIdx.x == 0) {
            double bd = 1e300; int bk = 0x7FFFFFFF;
#pragma unroll
            for (int j = 0; j < 3; ++j) {
                const int k = (packed >> (10 * j)) & 1023;
                const double d = part[j][0] + part[j][1] + part[j][2] + part[j][3];
                if (d < bd || (d == bd && k < bk)) { bd = d; bk = k; }
            }
            idx[n] = bk;
        }
        __syncthreads();
    }
}

// ---------- refineF: exact fp64 over all 1024 (rare 3-way bands) ----------
__launch_bounds__(256)
__global__ void refineF_kernel(const float* __restrict__ z, const float* __restrict__ cb,
                               int* __restrict__ idx, const int* __restrict__ cntF,
                               const int* __restrict__ listF) {
    __shared__ double zd[256];
    __shared__ double rv[256];
    __shared__ int    ri[256];
    int cnt = *cntF; if (cnt > NQ) cnt = NQ;
    for (int i = blockIdx.x; i < cnt; i += gridDim.x) {
        const int n = listF[i];
        const int b = n >> 12, t = n & 4095;
        __syncthreads();
        zd[threadIdx.x] = (double)z[(size_t)b * 1048576 + (size_t)threadIdx.x * 4096 + t];
        __syncthreads();
        double bestv = 1e300; int besti = 0;
        for (int j = 0; j < 4; ++j) {
            const int k = threadIdx.x * 4 + j;
            const float* crow = cb + (size_t)k * 256;
            double s = 0.0;
            for (int d = 0; d < 256; ++d) {
                const double diff = zd[d] - (double)crow[d];
                s = fma(diff, diff, s);
            }
            if (s < bestv) { bestv = s; besti = k; }
        }
        rv[threadIdx.x] = bestv; ri[threadIdx.x] = besti;
        __syncthreads();
        for (int off = 128; off; off >>= 1) {
            if (threadIdx.x < off) {
                const double ov = rv[threadIdx.x + off];
                const int    oi = ri[threadIdx.x + off];
                if (ov < rv[threadIdx.x] || (ov == rv[threadIdx.x] && oi < ri[threadIdx.x])) {
                    rv[threadIdx.x] = ov; ri[threadIdx.x] = oi;
                }
            }
            __syncthreads();
        }
        if (threadIdx.x == 0) idx[n] = ri[0];
        __syncthreads();
    }
}

// ---------- gather: out[b][d][t] = cb[idx[n]][d] ----------
__launch_bounds__(256)
__global__ void gather_kernel(const float* __restrict__ cb, const int* __restrict__ idx,
                              float* __restrict__ out) {
    const int tid = threadIdx.x;
    const int b = blockIdx.x >> 6, t0 = (blockIdx.x & 63) * 64;
    const int t = tid & 63, dq = tid >> 6;
    const int ki = idx[b * 4096 + t0 + t];
    const float4* row = (const float4*)(cb + (size_t)ki * 256 + dq * 64);
    float* ob = out + (size_t)b * 1048576 + (size_t)dq * 64 * 4096 + t0 + t;
#pragma unroll
    for (int i = 0; i < 16; ++i) {
        const float4 v = row[i];
        ob[(size_t)(i * 4 + 0) * 4096] = v.x;
        ob[(size_t)(i * 4 + 1) * 4096] = v.y;
        ob[(size_t)(i * 4 + 2) * 4096] = v.z;
        ob[(size_t)(i * 4 + 3) * 4096] = v.w;
    }
}

extern "C" void kernel_launch(void* const* d_in, const int* in_sizes, int n_in,
                              void* d_out, int out_size, void* d_ws, size_t ws_size,
                              hipStream_t stream) {
    (void)in_sizes; (void)n_in; (void)out_size; (void)ws_size;
    const float* z  = (const float*)d_in[0];
    const float* cb = (const float*)d_in[1];
    float* out = (float*)d_out;

    char* ws = (char*)d_ws;
    unsigned short* ch   = (unsigned short*)ws;                          // 512KB
    unsigned short* cl   = (unsigned short*)(ws + (512 << 10));          // 512KB
    float* csq_s         = (float*)(ws + (1024 << 10));                  // 4KB
    int*   idx           = (int*)(ws + (1024 << 10) + 4096);             // 256KB
    int*   cnts          = (int*)(ws + (1024 << 10) + 4096 + (256 << 10)); // 256B
    int*   list3         = (int*)((char*)cnts + 256);                    // 512KB
    int*   listF         = (int*)((char*)list3 + (512 << 10));           // 256KB
    unsigned short* zh   = (unsigned short*)d_out;                       // 32MB scratch in d_out

    hipMemsetAsync(cnts, 0, 256, stream);
    prep_cb<<<KCB, 64, 0, stream>>>(cb, ch, cl, csq_s);
    prep_z<<<1024, 256, 0, stream>>>(z, zh);
    gemm_argmin<<<NQ / 64, 256, 0, stream>>>(zh, ch, cl, csq_s, idx,
                                             &cnts[0], list3, &cnts[1], listF);
    refine3_kernel<<<1024, 256, 0, stream>>>(z, cb, idx, &cnts[0], list3);
    refineF_kernel<<<64, 256, 0, stream>>>(z, cb, idx, &cnts[1], listF);
    gather_kernel<<<1024, 256, 0, stream>>>(cb, idx, out);
}